// Round 1
// baseline (3991.521 us; speedup 1.0000x reference)
//
#include <hip/hip_runtime.h>

// GPT-2 small forward on MI355X. bf16 MFMA GEMMs (fp32 accum), fp32 residual
// stream + LayerNorms. Weights transposed+converted to bf16 in ws each launch.

#define CN    768
#define NKV   2304
#define FCN   3072
#define TN    1024
#define BN    4
#define HN    12
#define NL    12
#define MTOT  4096   // B*T

typedef __attribute__((ext_vector_type(4))) float f32x4;
typedef __attribute__((ext_vector_type(8))) short short8;

__device__ __forceinline__ unsigned short f2b(float f) {
    unsigned int u = __float_as_uint(f);
    u += 0x7fffu + ((u >> 16) & 1u);          // RNE
    return (unsigned short)(u >> 16);
}
__device__ __forceinline__ float b2f(unsigned short h) {
    return __uint_as_float(((unsigned int)h) << 16);
}

// ---------------- core 64x64 bf16 MFMA tile (BK=32) ----------------
// A: [M,K] bf16 row-major (lda), B: W^T layout [N,K] bf16 row-major (ldb).
// Wave w computes rows [w*16, w*16+16) x all 64 cols -> 4 accum frags.
__device__ __forceinline__ void gemm_core64(
        const unsigned short* __restrict__ A, int lda,
        const unsigned short* __restrict__ B, int ldb,
        int m0, int n0, int kmax, f32x4* acc)
{
    __shared__ __align__(16) unsigned short As[64 * 40];  // [m][k], +8 pad
    __shared__ __align__(16) unsigned short Bs[64 * 40];  // [n][k], +8 pad
    const int tid  = threadIdx.x;
    const int wave = tid >> 6;
    const int lane = tid & 63;
    const int quad = lane >> 4;
    const int l16  = lane & 15;
    const int srow = tid >> 2;          // 0..63
    const int scol = (tid & 3) << 3;    // 0,8,16,24
    const unsigned short* ag = A + (long)(m0 + srow) * lda + scol;
    const unsigned short* bg = B + (long)(n0 + srow) * ldb + scol;
    unsigned short* asw = &As[srow * 40 + scol];
    unsigned short* bsw = &Bs[srow * 40 + scol];
    const int aoff = (wave * 16 + l16) * 40 + quad * 8;

    for (int k0 = 0; k0 < kmax; k0 += 32) {
        int4 av = *(const int4*)(ag + k0);
        int4 bv = *(const int4*)(bg + k0);
        __syncthreads();                 // WAR: prior frag reads done
        *(int4*)asw = av;
        *(int4*)bsw = bv;
        __syncthreads();
        short8 af = *(const short8*)(As + aoff);
#pragma unroll
        for (int f = 0; f < 4; ++f) {
            short8 bf = *(const short8*)(Bs + (f * 16 + l16) * 40 + quad * 8);
            acc[f] = __builtin_amdgcn_mfma_f32_16x16x32_bf16(af, bf, acc[f], 0, 0, 0);
        }
    }
}

// C/D frag mapping: value r of lane -> row = wave*16 + quad*4 + r, col = f*16 + l16.

// ---------------- GEMM wrappers ----------------
// QKV: [4096,768] @ [768->2304] + bias, split-write q/k [B,H,T,D], vT [B,H,D,T]
__global__ __launch_bounds__(256) void k_gemm_qkv(
        const unsigned short* __restrict__ A, const unsigned short* __restrict__ B,
        const float* __restrict__ bias,
        unsigned short* __restrict__ qb, unsigned short* __restrict__ kb,
        unsigned short* __restrict__ vt)
{
    f32x4 acc[4];
#pragma unroll
    for (int f = 0; f < 4; ++f) acc[f] = 0.f;
    const int m0 = blockIdx.x * 64, n0 = blockIdx.y * 64;
    gemm_core64(A, CN, B, CN, m0, n0, CN, acc);
    const int wave = threadIdx.x >> 6, lane = threadIdx.x & 63;
    const int quad = lane >> 4, l16 = lane & 15;
#pragma unroll
    for (int f = 0; f < 4; ++f) {
        int col = n0 + f * 16 + l16;          // 0..2303
        float bv = bias[col];
        int which = col / CN;
        int cc = col - which * CN;
        int h = cc >> 6, d = cc & 63;
#pragma unroll
        for (int r = 0; r < 4; ++r) {
            int row = m0 + wave * 16 + quad * 4 + r;   // bt
            int b = row >> 10, t = row & 1023;
            int bh = b * HN + h;
            unsigned short val = f2b(acc[f][r] + bv);
            if (which == 0)      qb[(bh * TN + t) * 64 + d] = val;
            else if (which == 1) kb[(bh * TN + t) * 64 + d] = val;
            else                 vt[(bh * 64 + d) * TN + t] = val;
        }
    }
}

// S = Q K^T * 0.125, batched over z=(b,h). Skip blocks above diagonal.
__global__ __launch_bounds__(256) void k_gemm_s(
        const unsigned short* __restrict__ qb, const unsigned short* __restrict__ kb,
        unsigned short* __restrict__ S)
{
    const int bm = blockIdx.x, bn = blockIdx.y, z = blockIdx.z;
    if (bn > bm) return;
    f32x4 acc[4];
#pragma unroll
    for (int f = 0; f < 4; ++f) acc[f] = 0.f;
    gemm_core64(qb + (long)z * TN * 64, 64, kb + (long)z * TN * 64, 64,
                bm * 64, bn * 64, 64, acc);
    unsigned short* Sb = S + (long)z * TN * TN;
    const int wave = threadIdx.x >> 6, lane = threadIdx.x & 63;
    const int quad = lane >> 4, l16 = lane & 15;
#pragma unroll
    for (int f = 0; f < 4; ++f) {
        int col = bn * 64 + f * 16 + l16;
#pragma unroll
        for (int r = 0; r < 4; ++r) {
            int row = bm * 64 + wave * 16 + quad * 4 + r;
            Sb[(long)row * TN + col] = f2b(acc[f][r] * 0.125f);
        }
    }
}

// Y = P V, batched; K clipped causally; writes into y [B,T,C] at col h*64.
__global__ __launch_bounds__(256) void k_gemm_pv(
        const unsigned short* __restrict__ P, const unsigned short* __restrict__ vt,
        unsigned short* __restrict__ y)
{
    const int bm = blockIdx.x, z = blockIdx.z;
    f32x4 acc[4];
#pragma unroll
    for (int f = 0; f < 4; ++f) acc[f] = 0.f;
    const int kmax = (bm + 1) * 64;
    gemm_core64(P + (long)z * TN * TN, TN, vt + (long)z * TN * 64, TN,
                bm * 64, 0, kmax, acc);
    const int b = z / HN, h = z - b * HN;
    unsigned short* yb = y + (long)b * TN * CN + h * 64;
    const int wave = threadIdx.x >> 6, lane = threadIdx.x & 63;
    const int quad = lane >> 4, l16 = lane & 15;
#pragma unroll
    for (int f = 0; f < 4; ++f) {
        int col = f * 16 + l16;   // d
#pragma unroll
        for (int r = 0; r < 4; ++r) {
            int row = bm * 64 + wave * 16 + quad * 4 + r;
            yb[(long)row * CN + col] = f2b(acc[f][r]);
        }
    }
}

// out(fp32) X[row,col] += A@B + bias  (proj and MLP-down, N=768)
__global__ __launch_bounds__(256) void k_gemm_res(
        const unsigned short* __restrict__ A, int lda,
        const unsigned short* __restrict__ B, int K,
        const float* __restrict__ bias, float* __restrict__ X)
{
    f32x4 acc[4];
#pragma unroll
    for (int f = 0; f < 4; ++f) acc[f] = 0.f;
    const int m0 = blockIdx.x * 64, n0 = blockIdx.y * 64;
    gemm_core64(A, lda, B, K, m0, n0, K, acc);
    const int wave = threadIdx.x >> 6, lane = threadIdx.x & 63;
    const int quad = lane >> 4, l16 = lane & 15;
#pragma unroll
    for (int f = 0; f < 4; ++f) {
        int col = n0 + f * 16 + l16;
        float bv = bias[col];
#pragma unroll
        for (int r = 0; r < 4; ++r) {
            int row = m0 + wave * 16 + quad * 4 + r;
            X[(long)row * CN + col] += acc[f][r] + bv;
        }
    }
}

// G = gelu(A@B + bias) -> bf16 [4096,3072]
__global__ __launch_bounds__(256) void k_gemm_gelu(
        const unsigned short* __restrict__ A, const unsigned short* __restrict__ B,
        const float* __restrict__ bias, unsigned short* __restrict__ G)
{
    f32x4 acc[4];
#pragma unroll
    for (int f = 0; f < 4; ++f) acc[f] = 0.f;
    const int m0 = blockIdx.x * 64, n0 = blockIdx.y * 64;
    gemm_core64(A, CN, B, CN, m0, n0, CN, acc);
    const int wave = threadIdx.x >> 6, lane = threadIdx.x & 63;
    const int quad = lane >> 4, l16 = lane & 15;
#pragma unroll
    for (int f = 0; f < 4; ++f) {
        int col = n0 + f * 16 + l16;
        float bv = bias[col];
#pragma unroll
        for (int r = 0; r < 4; ++r) {
            int row = m0 + wave * 16 + quad * 4 + r;
            float u = acc[f][r] + bv;
            float c = 0.7978845608028654f * (u + 0.044715f * u * u * u);
            float g = 0.5f * u * (1.0f + tanhf(c));
            G[(long)row * FCN + col] = f2b(g);
        }
    }
}

// ---------------- small kernels ----------------
__device__ __forceinline__ float blk_sum(float v, float* red) {
#pragma unroll
    for (int o = 32; o > 0; o >>= 1) v += __shfl_xor(v, o);
    if ((threadIdx.x & 63) == 0) red[threadIdx.x >> 6] = v;
    __syncthreads();
    v = red[0] + red[1] + red[2] + red[3];
    __syncthreads();
    return v;
}

__global__ __launch_bounds__(256) void k_ln(
        const float* __restrict__ X, const float* __restrict__ w,
        const float* __restrict__ b, unsigned short* __restrict__ O)
{
    __shared__ float red[4];
    const int row = blockIdx.x, tid = threadIdx.x;
    const float* xr = X + (long)row * CN;
    float v[3], s = 0.f, sq = 0.f;
#pragma unroll
    for (int i = 0; i < 3; ++i) {
        v[i] = xr[tid + i * 256];
        s += v[i]; sq += v[i] * v[i];
    }
    s  = blk_sum(s, red);
    sq = blk_sum(sq, red);
    const float mu = s * (1.0f / CN);
    const float var = sq * (1.0f / CN) - mu * mu;
    const float rstd = rsqrtf(var + 1e-5f);
    unsigned short* orow = O + (long)row * CN;
#pragma unroll
    for (int i = 0; i < 3; ++i) {
        int c = tid + i * 256;
        orow[c] = f2b((v[i] - mu) * rstd * w[c] + b[c]);
    }
}

// causal softmax in place on bf16 S rows; zero-fill (q, ceil64(q+1))
__global__ __launch_bounds__(256) void k_softmax(unsigned short* __restrict__ S)
{
    __shared__ float buf[TN];
    __shared__ float red[4];
    const int bx = blockIdx.x;
    const int z = bx >> 10, q = bx & 1023;
    unsigned short* row = S + (long)z * TN * TN + (long)q * TN;
    const int n = q + 1, tid = threadIdx.x;
    float m = -1e30f;
    for (int i = tid; i < n; i += 256) {
        float v = b2f(row[i]);
        buf[i] = v;
        m = fmaxf(m, v);
    }
#pragma unroll
    for (int o = 32; o > 0; o >>= 1) m = fmaxf(m, __shfl_xor(m, o));
    if ((tid & 63) == 0) red[tid >> 6] = m;
    __syncthreads();
    m = fmaxf(fmaxf(red[0], red[1]), fmaxf(red[2], red[3]));
    __syncthreads();
    float s = 0.f;
    for (int i = tid; i < n; i += 256) {
        float e = __expf(buf[i] - m);
        buf[i] = e;
        s += e;
    }
    s = blk_sum(s, red);
    const float inv = 1.0f / s;
    for (int i = tid; i < n; i += 256) row[i] = f2b(buf[i] * inv);
    const int end = (n + 63) & ~63;
    for (int i = n + tid; i < end; i += 256) row[i] = 0;
}

// final LN + head dot (w_head [768,1]) -> out[row] fp32
__global__ __launch_bounds__(256) void k_final(
        const float* __restrict__ X, const float* __restrict__ w,
        const float* __restrict__ b, const float* __restrict__ wh,
        float* __restrict__ out)
{
    __shared__ float red[4];
    const int row = blockIdx.x, tid = threadIdx.x;
    const float* xr = X + (long)row * CN;
    float v[3], s = 0.f, sq = 0.f;
#pragma unroll
    for (int i = 0; i < 3; ++i) {
        v[i] = xr[tid + i * 256];
        s += v[i]; sq += v[i] * v[i];
    }
    s  = blk_sum(s, red);
    sq = blk_sum(sq, red);
    const float mu = s * (1.0f / CN);
    const float rstd = rsqrtf(sq * (1.0f / CN) - mu * mu + 1e-5f);
    float acc = 0.f;
#pragma unroll
    for (int i = 0; i < 3; ++i) {
        int c = tid + i * 256;
        acc += ((v[i] - mu) * rstd * w[c] + b[c]) * wh[c];
    }
    acc = blk_sum(acc, red);
    if (tid == 0) out[row] = acc;
}

// x = wte[idx] + wpe
__global__ __launch_bounds__(256) void k_embed(
        const int* __restrict__ idx, const float* __restrict__ wte,
        const float* __restrict__ wpe, float* __restrict__ X)
{
    long e = (long)blockIdx.x * 256 + threadIdx.x;   // < 4096*768
    int c = (int)(e % CN);
    int bt = (int)(e / CN);
    int t = bt & 1023;
    int tok = idx[bt];
    X[e] = wte[(long)tok * CN + c] + wpe[(long)t * CN + c];
}

// fp32 [K,N] -> bf16 [N,K] (per layer z), 32x32 LDS tile
__global__ __launch_bounds__(256) void k_transpose(
        const float* __restrict__ in, unsigned short* __restrict__ out, int K, int N)
{
    __shared__ float tile[32][33];
    const int z = blockIdx.z;
    in  += (long)z * K * N;
    out += (long)z * K * N;
    const int n0 = blockIdx.x * 32, k0 = blockIdx.y * 32;
    const int tx = threadIdx.x & 31, ty = threadIdx.x >> 5;   // 32 x 8
#pragma unroll
    for (int i = 0; i < 4; ++i)
        tile[ty + i * 8][tx] = in[(long)(k0 + ty + i * 8) * N + n0 + tx];
    __syncthreads();
#pragma unroll
    for (int i = 0; i < 4; ++i)
        out[(long)(n0 + ty + i * 8) * K + k0 + tx] = f2b(tile[tx][ty + i * 8]);
}

// ---------------- host ----------------
extern "C" void kernel_launch(void* const* d_in, const int* in_sizes, int n_in,
                              void* d_out, int out_size, void* d_ws, size_t ws_size,
                              hipStream_t stream)
{
    const int*   idx    = (const int*)  d_in[0];
    const float* wte    = (const float*)d_in[1];
    const float* wpe    = (const float*)d_in[2];
    const float* ln1_w  = (const float*)d_in[3];
    const float* ln1_b  = (const float*)d_in[4];
    const float* w_qkv  = (const float*)d_in[5];
    const float* b_qkv  = (const float*)d_in[6];
    const float* w_ao   = (const float*)d_in[7];
    const float* b_ao   = (const float*)d_in[8];
    const float* ln2_w  = (const float*)d_in[9];
    const float* ln2_b  = (const float*)d_in[10];
    const float* w_fc   = (const float*)d_in[11];
    const float* b_fc   = (const float*)d_in[12];
    const float* w_fp   = (const float*)d_in[13];
    const float* b_fp   = (const float*)d_in[14];
    const float* lnf_w  = (const float*)d_in[15];
    const float* lnf_b  = (const float*)d_in[16];
    const float* w_head = (const float*)d_in[17];
    float* out = (float*)d_out;

    char* ws = (char*)d_ws;
    unsigned short* wqkvT = (unsigned short*)(ws + 0L);
    unsigned short* waoT  = (unsigned short*)(ws + 42467328L);
    unsigned short* wfcT  = (unsigned short*)(ws + 56623104L);
    unsigned short* wfpT  = (unsigned short*)(ws + 113246208L);
    float*          x     = (float*)         (ws + 169869312L);
    unsigned short* hb    = (unsigned short*)(ws + 182452224L);
    unsigned short* qb    = (unsigned short*)(ws + 188743680L);
    unsigned short* kb    = (unsigned short*)(ws + 195035136L);
    unsigned short* vt    = (unsigned short*)(ws + 201326592L);
    unsigned short* S     = (unsigned short*)(ws + 207618048L);
    unsigned short* y     = (unsigned short*)(ws + 308281344L);
    unsigned short* g     = (unsigned short*)(ws + 314572800L);
    // total ws use: 339738624 bytes

    // weight convert+transpose (once per launch)
    hipLaunchKernelGGL(k_transpose, dim3(NKV / 32, CN / 32, NL), dim3(256), 0, stream,
                       w_qkv, wqkvT, CN, NKV);
    hipLaunchKernelGGL(k_transpose, dim3(CN / 32, CN / 32, NL), dim3(256), 0, stream,
                       w_ao, waoT, CN, CN);
    hipLaunchKernelGGL(k_transpose, dim3(FCN / 32, CN / 32, NL), dim3(256), 0, stream,
                       w_fc, wfcT, CN, FCN);
    hipLaunchKernelGGL(k_transpose, dim3(CN / 32, FCN / 32, NL), dim3(256), 0, stream,
                       w_fp, wfpT, FCN, CN);

    hipLaunchKernelGGL(k_embed, dim3(MTOT * CN / 256), dim3(256), 0, stream,
                       idx, wte, wpe, x);

    for (int l = 0; l < NL; ++l) {
        hipLaunchKernelGGL(k_ln, dim3(MTOT), dim3(256), 0, stream,
                           x, ln1_w + l * CN, ln1_b + l * CN, hb);
        hipLaunchKernelGGL(k_gemm_qkv, dim3(MTOT / 64, NKV / 64), dim3(256), 0, stream,
                           hb, wqkvT + (long)l * NKV * CN, b_qkv + l * NKV, qb, kb, vt);
        hipLaunchKernelGGL(k_gemm_s, dim3(TN / 64, TN / 64, BN * HN), dim3(256), 0, stream,
                           qb, kb, S);
        hipLaunchKernelGGL(k_softmax, dim3(BN * HN * TN), dim3(256), 0, stream, S);
        hipLaunchKernelGGL(k_gemm_pv, dim3(TN / 64, 1, BN * HN), dim3(256), 0, stream,
                           S, vt, y);
        hipLaunchKernelGGL(k_gemm_res, dim3(MTOT / 64, CN / 64), dim3(256), 0, stream,
                           y, CN, waoT + (long)l * CN * CN, CN, b_ao + l * CN, x);
        hipLaunchKernelGGL(k_ln, dim3(MTOT), dim3(256), 0, stream,
                           x, ln2_w + l * CN, ln2_b + l * CN, hb);
        hipLaunchKernelGGL(k_gemm_gelu, dim3(MTOT / 64, FCN / 64), dim3(256), 0, stream,
                           hb, wfcT + (long)l * FCN * CN, b_fc + l * FCN, g);
        hipLaunchKernelGGL(k_gemm_res, dim3(MTOT / 64, CN / 64), dim3(256), 0, stream,
                           g, FCN, wfpT + (long)l * FCN * CN, FCN, b_fp + l * CN, x);
    }

    hipLaunchKernelGGL(k_final, dim3(MTOT), dim3(256), 0, stream,
                       x, lnf_w, lnf_b, w_head, out);
}

// Round 2
// 3851.109 us; speedup vs baseline: 1.0365x; 1.0365x over previous
//
#include <hip/hip_runtime.h>

// GPT-2 small forward on MI355X. bf16 MFMA GEMMs (fp32 accum), fp32 residual
// stream + LayerNorms. Dense GEMMs use m97-style 128x128 tiles with
// global_load_lds width-16 staging; PV uses a 64x64 core (N=64).

#define CN    768
#define NKV   2304
#define FCN   3072
#define TN    1024
#define BN    4
#define HN    12
#define NL    12
#define MTOT  4096   // B*T

typedef __attribute__((ext_vector_type(4))) float f32x4;
typedef __attribute__((ext_vector_type(8))) short short8;

typedef const __attribute__((address_space(1))) void* gas_t;
typedef __attribute__((address_space(3))) void* las_t;

__device__ __forceinline__ unsigned short f2b(float f) {
    unsigned int u = __float_as_uint(f);
    u += 0x7fffu + ((u >> 16) & 1u);          // RNE
    return (unsigned short)(u >> 16);
}
__device__ __forceinline__ float b2f(unsigned short h) {
    return __uint_as_float(((unsigned int)h) << 16);
}

// ---------------- 128x128 bf16 MFMA core (BK=32, global_load_lds) ----------
// A [M,K] bf16 row-major lda; B [N,K] bf16 row-major ldb (i.e. W^T layout).
// 256 threads = 4 waves in 2x2; wave covers 64x64 via 4x4 16x16x32 frags.
// LDS unpadded [128][32] (required: global_load_lds dest = wave base+lane*16).
__device__ __forceinline__ void gemm128(
        const unsigned short* __restrict__ A, int lda,
        const unsigned short* __restrict__ B, int ldb,
        int m0, int n0, int kbeg, int kend, f32x4 acc[4][4])
{
    __shared__ __align__(16) unsigned short As[128 * 32];
    __shared__ __align__(16) unsigned short Bs[128 * 32];
    const int tid  = threadIdx.x;
    const int wave = tid >> 6;
    const int lane = tid & 63;
    const int quad = lane >> 4;
    const int l16  = lane & 15;
    const int wm   = (wave & 1) * 64;
    const int wn   = (wave >> 1) * 64;
    // staging: chunk it in {0,1}: row = it*64 + wave*16 + lane/4, col8=(lane&3)*8
    const int srow = wave * 16 + (lane >> 2);
    const int scol = (lane & 3) << 3;
    const unsigned short* ag = A + (long)(m0 + srow) * lda + scol;
    const unsigned short* bg = B + (long)(n0 + srow) * ldb + scol;
    unsigned short* asw = As + wave * 512;      // +lane*8 implicit in HW
    unsigned short* bsw = Bs + wave * 512;

    for (int k0 = kbeg; k0 < kend; k0 += 32) {
        __syncthreads();                        // WAR vs prior frag reads
        __builtin_amdgcn_global_load_lds((gas_t)(ag + k0),                  (las_t)(asw),            16, 0, 0);
        __builtin_amdgcn_global_load_lds((gas_t)(ag + k0 + (long)64 * lda), (las_t)(asw + 64 * 32),  16, 0, 0);
        __builtin_amdgcn_global_load_lds((gas_t)(bg + k0),                  (las_t)(bsw),            16, 0, 0);
        __builtin_amdgcn_global_load_lds((gas_t)(bg + k0 + (long)64 * ldb), (las_t)(bsw + 64 * 32),  16, 0, 0);
        __syncthreads();                        // compiler adds vmcnt(0) drain
        short8 af[4], bf[4];
#pragma unroll
        for (int i = 0; i < 4; ++i)
            af[i] = *(const short8*)(As + (wm + i * 16 + l16) * 32 + quad * 8);
#pragma unroll
        for (int j = 0; j < 4; ++j)
            bf[j] = *(const short8*)(Bs + (wn + j * 16 + l16) * 32 + quad * 8);
#pragma unroll
        for (int i = 0; i < 4; ++i)
#pragma unroll
            for (int j = 0; j < 4; ++j)
                acc[i][j] = __builtin_amdgcn_mfma_f32_16x16x32_bf16(af[i], bf[j], acc[i][j], 0, 0, 0);
    }
}
// C/D: value r of acc[i][j] -> row = m0+wm+i*16+quad*4+r, col = n0+wn+j*16+l16.

// ---------------- 64x64 core (for PV, N=64) ----------------
__device__ __forceinline__ void gemm_core64(
        const unsigned short* __restrict__ A, int lda,
        const unsigned short* __restrict__ B, int ldb,
        int m0, int n0, int kmax, f32x4* acc)
{
    __shared__ __align__(16) unsigned short As[64 * 40];
    __shared__ __align__(16) unsigned short Bs[64 * 40];
    const int tid  = threadIdx.x;
    const int wave = tid >> 6;
    const int lane = tid & 63;
    const int quad = lane >> 4;
    const int l16  = lane & 15;
    const int srow = tid >> 2;
    const int scol = (tid & 3) << 3;
    const unsigned short* ag = A + (long)(m0 + srow) * lda + scol;
    const unsigned short* bg = B + (long)(n0 + srow) * ldb + scol;
    unsigned short* asw = &As[srow * 40 + scol];
    unsigned short* bsw = &Bs[srow * 40 + scol];
    const int aoff = (wave * 16 + l16) * 40 + quad * 8;

    for (int k0 = 0; k0 < kmax; k0 += 32) {
        int4 av = *(const int4*)(ag + k0);
        int4 bv = *(const int4*)(bg + k0);
        __syncthreads();
        *(int4*)asw = av;
        *(int4*)bsw = bv;
        __syncthreads();
        short8 af = *(const short8*)(As + aoff);
#pragma unroll
        for (int f = 0; f < 4; ++f) {
            short8 bf = *(const short8*)(Bs + (f * 16 + l16) * 40 + quad * 8);
            acc[f] = __builtin_amdgcn_mfma_f32_16x16x32_bf16(af, bf, acc[f], 0, 0, 0);
        }
    }
}

// ---------------- GEMM kernels ----------------
// QKV: [4096,768] @ W^T[2304,768] + bias -> split q/k [B,H,T,D], vT [B,H,D,T]
__global__ __launch_bounds__(256) void k_qkv128(
        const unsigned short* __restrict__ A, const unsigned short* __restrict__ B,
        const float* __restrict__ bias,
        unsigned short* __restrict__ qb, unsigned short* __restrict__ kb,
        unsigned short* __restrict__ vt)
{
    f32x4 acc[4][4];
#pragma unroll
    for (int i = 0; i < 4; ++i)
#pragma unroll
        for (int j = 0; j < 4; ++j) acc[i][j] = 0.f;
    const int m0 = blockIdx.x * 128, n0 = blockIdx.y * 128;
    gemm128(A, CN, B, CN, m0, n0, 0, CN, acc);
    const int wave = threadIdx.x >> 6, lane = threadIdx.x & 63;
    const int quad = lane >> 4, l16 = lane & 15;
    const int wm = (wave & 1) * 64, wn = (wave >> 1) * 64;
#pragma unroll
    for (int j = 0; j < 4; ++j) {
        int col = n0 + wn + j * 16 + l16;
        float bv = bias[col];
        int which = col / CN;
        int cc = col - which * CN;
        int h = cc >> 6, d = cc & 63;
#pragma unroll
        for (int i = 0; i < 4; ++i) {
#pragma unroll
            for (int r = 0; r < 4; ++r) {
                int row = m0 + wm + i * 16 + quad * 4 + r;
                int b = row >> 10, t = row & 1023;
                int bh = b * HN + h;
                unsigned short val = f2b(acc[i][j][r] + bv);
                if (which == 0)      qb[(bh * TN + t) * 64 + d] = val;
                else if (which == 1) kb[(bh * TN + t) * 64 + d] = val;
                else                 vt[(bh * 64 + d) * TN + t] = val;
            }
        }
    }
}

// S = Q K^T * 0.125, z=(b,h), 128x128 tiles, skip above diagonal.
__global__ __launch_bounds__(256) void k_s128(
        const unsigned short* __restrict__ qb, const unsigned short* __restrict__ kb,
        unsigned short* __restrict__ S)
{
    const int bm = blockIdx.x, bn = blockIdx.y, z = blockIdx.z;
    if (bn > bm) return;
    f32x4 acc[4][4];
#pragma unroll
    for (int i = 0; i < 4; ++i)
#pragma unroll
        for (int j = 0; j < 4; ++j) acc[i][j] = 0.f;
    gemm128(qb + (long)z * TN * 64, 64, kb + (long)z * TN * 64, 64,
            bm * 128, bn * 128, 0, 64, acc);
    unsigned short* Sb = S + (long)z * TN * TN;
    const int wave = threadIdx.x >> 6, lane = threadIdx.x & 63;
    const int quad = lane >> 4, l16 = lane & 15;
    const int wm = (wave & 1) * 64, wn = (wave >> 1) * 64;
#pragma unroll
    for (int j = 0; j < 4; ++j) {
        int col = bn * 128 + wn + j * 16 + l16;
#pragma unroll
        for (int i = 0; i < 4; ++i)
#pragma unroll
            for (int r = 0; r < 4; ++r) {
                int row = bm * 128 + wm + i * 16 + quad * 4 + r;
                Sb[(long)row * TN + col] = f2b(acc[i][j][r] * 0.125f);
            }
    }
}

// FC: gelu(A@W^T + bias) -> bf16 [4096,3072]
__global__ __launch_bounds__(256) void k_fc128(
        const unsigned short* __restrict__ A, const unsigned short* __restrict__ B,
        const float* __restrict__ bias, unsigned short* __restrict__ G)
{
    f32x4 acc[4][4];
#pragma unroll
    for (int i = 0; i < 4; ++i)
#pragma unroll
        for (int j = 0; j < 4; ++j) acc[i][j] = 0.f;
    const int m0 = blockIdx.x * 128, n0 = blockIdx.y * 128;
    gemm128(A, CN, B, CN, m0, n0, 0, CN, acc);
    const int wave = threadIdx.x >> 6, lane = threadIdx.x & 63;
    const int quad = lane >> 4, l16 = lane & 15;
    const int wm = (wave & 1) * 64, wn = (wave >> 1) * 64;
#pragma unroll
    for (int j = 0; j < 4; ++j) {
        int col = n0 + wn + j * 16 + l16;
        float bv = bias[col];
#pragma unroll
        for (int i = 0; i < 4; ++i)
#pragma unroll
            for (int r = 0; r < 4; ++r) {
                int row = m0 + wm + i * 16 + quad * 4 + r;
                float u = acc[i][j][r] + bv;
                float c = 0.7978845608028654f * (u + 0.044715f * u * u * u);
                float g = 0.5f * u * (1.0f + tanhf(c));
                G[(long)row * FCN + col] = f2b(g);
            }
    }
}

// Residual GEMM with split-K: X += A@W^T (+bias on kz==0), fp32 atomics.
__global__ __launch_bounds__(256) void k_res128(
        const unsigned short* __restrict__ A, int lda,
        const unsigned short* __restrict__ B, int K, int ksplit,
        const float* __restrict__ bias, float* __restrict__ X)
{
    f32x4 acc[4][4];
#pragma unroll
    for (int i = 0; i < 4; ++i)
#pragma unroll
        for (int j = 0; j < 4; ++j) acc[i][j] = 0.f;
    const int m0 = blockIdx.x * 128, n0 = blockIdx.y * 128;
    const int kz = blockIdx.z;
    const int klen = K / ksplit;
    gemm128(A, lda, B, K, m0, n0, kz * klen, kz * klen + klen, acc);
    const int wave = threadIdx.x >> 6, lane = threadIdx.x & 63;
    const int quad = lane >> 4, l16 = lane & 15;
    const int wm = (wave & 1) * 64, wn = (wave >> 1) * 64;
#pragma unroll
    for (int j = 0; j < 4; ++j) {
        int col = n0 + wn + j * 16 + l16;
        float bv = (kz == 0) ? bias[col] : 0.f;
#pragma unroll
        for (int i = 0; i < 4; ++i)
#pragma unroll
            for (int r = 0; r < 4; ++r) {
                int row = m0 + wm + i * 16 + quad * 4 + r;
                atomicAdd(&X[(long)row * CN + col], acc[i][j][r] + bv);
            }
    }
}

// Y = P V (64x64 core), K clipped causally; writes y [B,T,C] at col h*64.
__global__ __launch_bounds__(256) void k_gemm_pv(
        const unsigned short* __restrict__ P, const unsigned short* __restrict__ vt,
        unsigned short* __restrict__ y)
{
    const int bm = blockIdx.x, z = blockIdx.z;
    f32x4 acc[4];
#pragma unroll
    for (int f = 0; f < 4; ++f) acc[f] = 0.f;
    const int kmax = (bm + 1) * 64;
    gemm_core64(P + (long)z * TN * TN, TN, vt + (long)z * TN * 64, TN,
                bm * 64, 0, kmax, acc);
    const int b = z / HN, h = z - b * HN;
    unsigned short* yb = y + (long)b * TN * CN + h * 64;
    const int wave = threadIdx.x >> 6, lane = threadIdx.x & 63;
    const int quad = lane >> 4, l16 = lane & 15;
#pragma unroll
    for (int f = 0; f < 4; ++f) {
        int col = f * 16 + l16;
#pragma unroll
        for (int r = 0; r < 4; ++r) {
            int row = bm * 64 + wave * 16 + quad * 4 + r;
            yb[(long)row * CN + col] = f2b(acc[f][r]);
        }
    }
}

// ---------------- small kernels ----------------
__device__ __forceinline__ float blk_sum(float v, float* red) {
#pragma unroll
    for (int o = 32; o > 0; o >>= 1) v += __shfl_xor(v, o);
    if ((threadIdx.x & 63) == 0) red[threadIdx.x >> 6] = v;
    __syncthreads();
    v = red[0] + red[1] + red[2] + red[3];
    __syncthreads();
    return v;
}

__global__ __launch_bounds__(256) void k_ln(
        const float* __restrict__ X, const float* __restrict__ w,
        const float* __restrict__ b, unsigned short* __restrict__ O)
{
    __shared__ float red[4];
    const int row = blockIdx.x, tid = threadIdx.x;
    const float* xr = X + (long)row * CN;
    float v[3], s = 0.f, sq = 0.f;
#pragma unroll
    for (int i = 0; i < 3; ++i) {
        v[i] = xr[tid + i * 256];
        s += v[i]; sq += v[i] * v[i];
    }
    s  = blk_sum(s, red);
    sq = blk_sum(sq, red);
    const float mu = s * (1.0f / CN);
    const float var = sq * (1.0f / CN) - mu * mu;
    const float rstd = rsqrtf(var + 1e-5f);
    unsigned short* orow = O + (long)row * CN;
#pragma unroll
    for (int i = 0; i < 3; ++i) {
        int c = tid + i * 256;
        orow[c] = f2b((v[i] - mu) * rstd * w[c] + b[c]);
    }
}

// causal softmax in place on bf16 S rows; zero-fill (q, min(ceil128(q+1),TN))
__global__ __launch_bounds__(256) void k_softmax(unsigned short* __restrict__ S)
{
    __shared__ float buf[TN];
    __shared__ float red[4];
    const int bx = blockIdx.x;
    const int z = bx >> 10, q = bx & 1023;
    unsigned short* row = S + (long)z * TN * TN + (long)q * TN;
    const int n = q + 1, tid = threadIdx.x;
    float m = -1e30f;
    for (int i = tid; i < n; i += 256) {
        float v = b2f(row[i]);
        buf[i] = v;
        m = fmaxf(m, v);
    }
#pragma unroll
    for (int o = 32; o > 0; o >>= 1) m = fmaxf(m, __shfl_xor(m, o));
    if ((tid & 63) == 0) red[tid >> 6] = m;
    __syncthreads();
    m = fmaxf(fmaxf(red[0], red[1]), fmaxf(red[2], red[3]));
    __syncthreads();
    float s = 0.f;
    for (int i = tid; i < n; i += 256) {
        float e = __expf(buf[i] - m);
        buf[i] = e;
        s += e;
    }
    s = blk_sum(s, red);
    const float inv = 1.0f / s;
    for (int i = tid; i < n; i += 256) row[i] = f2b(buf[i] * inv);
    int end = (n + 127) & ~127;
    if (end > TN) end = TN;
    for (int i = n + tid; i < end; i += 256) row[i] = 0;
}

// final LN + head dot (w_head [768,1]) -> out[row] fp32
__global__ __launch_bounds__(256) void k_final(
        const float* __restrict__ X, const float* __restrict__ w,
        const float* __restrict__ b, const float* __restrict__ wh,
        float* __restrict__ out)
{
    __shared__ float red[4];
    const int row = blockIdx.x, tid = threadIdx.x;
    const float* xr = X + (long)row * CN;
    float v[3], s = 0.f, sq = 0.f;
#pragma unroll
    for (int i = 0; i < 3; ++i) {
        v[i] = xr[tid + i * 256];
        s += v[i]; sq += v[i] * v[i];
    }
    s  = blk_sum(s, red);
    sq = blk_sum(sq, red);
    const float mu = s * (1.0f / CN);
    const float rstd = rsqrtf(sq * (1.0f / CN) - mu * mu + 1e-5f);
    float acc = 0.f;
#pragma unroll
    for (int i = 0; i < 3; ++i) {
        int c = tid + i * 256;
        acc += ((v[i] - mu) * rstd * w[c] + b[c]) * wh[c];
    }
    acc = blk_sum(acc, red);
    if (tid == 0) out[row] = acc;
}

// x = wte[idx] + wpe
__global__ __launch_bounds__(256) void k_embed(
        const int* __restrict__ idx, const float* __restrict__ wte,
        const float* __restrict__ wpe, float* __restrict__ X)
{
    long e = (long)blockIdx.x * 256 + threadIdx.x;
    int c = (int)(e % CN);
    int bt = (int)(e / CN);
    int t = bt & 1023;
    int tok = idx[bt];
    X[e] = wte[(long)tok * CN + c] + wpe[(long)t * CN + c];
}

// fp32 [K,N] -> bf16 [N,K] (per layer z), 32x32 LDS tile
__global__ __launch_bounds__(256) void k_transpose(
        const float* __restrict__ in, unsigned short* __restrict__ out, int K, int N)
{
    __shared__ float tile[32][33];
    const int z = blockIdx.z;
    in  += (long)z * K * N;
    out += (long)z * K * N;
    const int n0 = blockIdx.x * 32, k0 = blockIdx.y * 32;
    const int tx = threadIdx.x & 31, ty = threadIdx.x >> 5;
#pragma unroll
    for (int i = 0; i < 4; ++i)
        tile[ty + i * 8][tx] = in[(long)(k0 + ty + i * 8) * N + n0 + tx];
    __syncthreads();
#pragma unroll
    for (int i = 0; i < 4; ++i)
        out[(long)(n0 + ty + i * 8) * K + k0 + tx] = f2b(tile[tx][ty + i * 8]);
}

// ---------------- host ----------------
extern "C" void kernel_launch(void* const* d_in, const int* in_sizes, int n_in,
                              void* d_out, int out_size, void* d_ws, size_t ws_size,
                              hipStream_t stream)
{
    const int*   idx    = (const int*)  d_in[0];
    const float* wte    = (const float*)d_in[1];
    const float* wpe    = (const float*)d_in[2];
    const float* ln1_w  = (const float*)d_in[3];
    const float* ln1_b  = (const float*)d_in[4];
    const float* w_qkv  = (const float*)d_in[5];
    const float* b_qkv  = (const float*)d_in[6];
    const float* w_ao   = (const float*)d_in[7];
    const float* b_ao   = (const float*)d_in[8];
    const float* ln2_w  = (const float*)d_in[9];
    const float* ln2_b  = (const float*)d_in[10];
    const float* w_fc   = (const float*)d_in[11];
    const float* b_fc   = (const float*)d_in[12];
    const float* w_fp   = (const float*)d_in[13];
    const float* b_fp   = (const float*)d_in[14];
    const float* lnf_w  = (const float*)d_in[15];
    const float* lnf_b  = (const float*)d_in[16];
    const float* w_head = (const float*)d_in[17];
    float* out = (float*)d_out;

    char* ws = (char*)d_ws;
    unsigned short* wqkvT = (unsigned short*)(ws + 0L);
    unsigned short* waoT  = (unsigned short*)(ws + 42467328L);
    unsigned short* wfcT  = (unsigned short*)(ws + 56623104L);
    unsigned short* wfpT  = (unsigned short*)(ws + 113246208L);
    float*          x     = (float*)         (ws + 169869312L);
    unsigned short* hb    = (unsigned short*)(ws + 182452224L);
    unsigned short* qb    = (unsigned short*)(ws + 188743680L);
    unsigned short* kb    = (unsigned short*)(ws + 195035136L);
    unsigned short* vt    = (unsigned short*)(ws + 201326592L);
    unsigned short* S     = (unsigned short*)(ws + 207618048L);
    unsigned short* y     = (unsigned short*)(ws + 308281344L);
    unsigned short* g     = (unsigned short*)(ws + 314572800L);

    hipLaunchKernelGGL(k_transpose, dim3(NKV / 32, CN / 32, NL), dim3(256), 0, stream,
                       w_qkv, wqkvT, CN, NKV);
    hipLaunchKernelGGL(k_transpose, dim3(CN / 32, CN / 32, NL), dim3(256), 0, stream,
                       w_ao, waoT, CN, CN);
    hipLaunchKernelGGL(k_transpose, dim3(FCN / 32, CN / 32, NL), dim3(256), 0, stream,
                       w_fc, wfcT, CN, FCN);
    hipLaunchKernelGGL(k_transpose, dim3(CN / 32, FCN / 32, NL), dim3(256), 0, stream,
                       w_fp, wfpT, FCN, CN);

    hipLaunchKernelGGL(k_embed, dim3(MTOT * CN / 256), dim3(256), 0, stream,
                       idx, wte, wpe, x);

    for (int l = 0; l < NL; ++l) {
        hipLaunchKernelGGL(k_ln, dim3(MTOT), dim3(256), 0, stream,
                           x, ln1_w + l * CN, ln1_b + l * CN, hb);
        hipLaunchKernelGGL(k_qkv128, dim3(MTOT / 128, NKV / 128), dim3(256), 0, stream,
                           hb, wqkvT + (long)l * NKV * CN, b_qkv + l * NKV, qb, kb, vt);
        hipLaunchKernelGGL(k_s128, dim3(TN / 128, TN / 128, BN * HN), dim3(256), 0, stream,
                           qb, kb, S);
        hipLaunchKernelGGL(k_softmax, dim3(BN * HN * TN), dim3(256), 0, stream, S);
        hipLaunchKernelGGL(k_gemm_pv, dim3(TN / 64, 1, BN * HN), dim3(256), 0, stream,
                           S, vt, y);
        hipLaunchKernelGGL(k_res128, dim3(MTOT / 128, CN / 128, 2), dim3(256), 0, stream,
                           y, CN, waoT + (long)l * CN * CN, CN, 2, b_ao + l * CN, x);
        hipLaunchKernelGGL(k_ln, dim3(MTOT), dim3(256), 0, stream,
                           x, ln2_w + l * CN, ln2_b + l * CN, hb);
        hipLaunchKernelGGL(k_fc128, dim3(MTOT / 128, FCN / 128), dim3(256), 0, stream,
                           hb, wfcT + (long)l * FCN * CN, b_fc + l * FCN, g);
        hipLaunchKernelGGL(k_res128, dim3(MTOT / 128, CN / 128, 4), dim3(256), 0, stream,
                           g, FCN, wfpT + (long)l * FCN * CN, FCN, 4, b_fp + l * CN, x);
    }

    hipLaunchKernelGGL(k_final, dim3(MTOT), dim3(256), 0, stream,
                       x, lnf_w, lnf_b, w_head, out);
}